// Round 2
// baseline (525.131 us; speedup 1.0000x reference)
//
#include <hip/hip_runtime.h>
#include <hip/hip_bf16.h>

// SparseConv2D: 32x112x112x128 fp32 NHWC, 3x3 SAME, 126 out channels each with
// 5 nonzero taps (patterns). Implicit GEMM on bf16 MFMA, dense-9-tap formulation.
//
// M = 112 (one image row, 7 x 16-tiles), N = 128 (126 padded), K = 9*128.
// Block = 256 thr (4 waves); wave w owns output cols [32w, 32w+32).
// K loop: cc in 0..3 (channel chunks of 32) x p in 0..8 (taps).
//   A: 3 rows x 114 px x 32 ch staged to LDS per cc (fp32->bf16 inline).
//   B: dense bf16 kernel built in d_ws by prep kernel, layout [p][cc][n][c],
//      32x128 chunk double-buffered in LDS with register prefetch.

typedef __attribute__((ext_vector_type(8))) __bf16 bf16x8;
typedef __attribute__((ext_vector_type(4))) float f32x4;

__device__ __forceinline__ unsigned short f2bf(float f) {
  unsigned int u = __builtin_bit_cast(unsigned int, f);
  u += 0x7fffu + ((u >> 16) & 1u);   // RNE (inputs are finite normals)
  return (unsigned short)(u >> 16);
}

// Bws[p][cc][n][c] bf16: dense kernel, n in [0,128) (126..127 zero), c in [0,32)
__global__ __launch_bounds__(256) void build_B(const float* __restrict__ sk,
                                               const int* __restrict__ patterns,
                                               unsigned short* __restrict__ Bws) {
  int idx = blockIdx.x * 256 + threadIdx.x;
  if (idx >= 9 * 128 * 128) return;
  int c = idx & 127;
  int n = (idx >> 7) & 127;
  int p = idx >> 14;
  float v = 0.f;
  if (n < 126) {
#pragma unroll
    for (int j = 0; j < 5; ++j)
      if (patterns[n * 5 + j] == p) v = sk[(j * 128 + c) * 126 + n];
  }
  int cc = c >> 5, cl = c & 31;
  Bws[(((p * 4 + cc) * 128) + n) * 32 + cl] = f2bf(v);
}

__global__ __launch_bounds__(256) void conv_main(const float* __restrict__ in,
                                                 const unsigned short* __restrict__ Bws,
                                                 const float* __restrict__ bias,
                                                 float* __restrict__ out) {
  // pad channel dim 32 -> 40 elements (80 B rows): frag reads are 2-way max on banks
  __shared__ unsigned short Alds[3 * 114 * 40];      // 27,360 B
  __shared__ unsigned short Blds[2][128 * 40];       // 20,480 B

  const int tid = threadIdx.x;
  const int bid = blockIdx.x;
  const int nimg = bid / 112;
  const int y = bid - nimg * 112;
  const int lane = tid & 63;
  const int w = tid >> 6;           // wave id: cols [32w, 32w+32)
  const int quad = lane >> 4;
  const int lrow = lane & 15;

  const float* inb = in + (size_t)nimg * 112 * 112 * 128;

  f32x4 acc[7][2];
#pragma unroll
  for (int mt = 0; mt < 7; ++mt) { acc[mt][0] = (f32x4)0.f; acc[mt][1] = (f32x4)0.f; }

  // stage A chunk: rows y-1..y+1, hx in [0,114) (gx = hx-1), 32 channels of chunk cc
  auto stageA = [&](int cc) {
#pragma unroll
    for (int it = 0; it < 11; ++it) {
      int i = tid + it * 256;                 // 3*114*8 = 2736 float4 loads
      if (i < 2736) {
        int c4 = i & 7;
        int rest = i >> 3;                    // hx + 114*r
        int r = rest / 114;
        int hx = rest - r * 114;
        int gy = y + r - 1;
        int gx = hx - 1;
        float4 v = make_float4(0.f, 0.f, 0.f, 0.f);
        if ((unsigned)gy < 112u && (unsigned)gx < 112u)
          v = *(const float4*)(inb + ((size_t)gy * 112 + gx) * 128 + cc * 32 + c4 * 4);
        ushort4 s;
        s.x = f2bf(v.x); s.y = f2bf(v.y); s.z = f2bf(v.z); s.w = f2bf(v.w);
        *(ushort4*)&Alds[(r * 114 + hx) * 40 + c4 * 4] = s;
      }
    }
  };

  // B staging: one 32x128 chunk = 128 rows x 64 B = 512 16-B pieces, 4 per row.
  // piece i: row n = i>>2, quarter q = i&3 (channels q*8 .. q*8+7).
  // thread handles pieces tid (rows 0..63) and tid+256 (rows 64..127).
  const int i0 = tid, i1 = tid + 256;
  const int d0 = (i0 >> 2) * 40 + (i0 & 3) * 8;
  const int d1 = (i1 >> 2) * 40 + (i1 & 3) * 8;
  auto bsrc = [&](int t, int i) -> const uint4* {
    int cc = t / 9, p = t - cc * 9;
    int n = i >> 2, q = i & 3;
    return (const uint4*)(Bws + (((p * 4 + cc) * 128 + n) * 32 + q * 8));
  };

  stageA(0);
  {
    uint4 pb0 = *bsrc(0, i0), pb1 = *bsrc(0, i1);
    *(uint4*)&Blds[0][d0] = pb0;
    *(uint4*)&Blds[0][d1] = pb1;
  }
  __syncthreads();

#pragma unroll 1
  for (int t = 0; t < 36; ++t) {
    const int cc = t / 9;
    const int p = t - cc * 9;
    const int buf = t & 1;
    const bool pre = (t < 35);
    uint4 nb0, nb1;
    if (pre) { nb0 = *bsrc(t + 1, i0); nb1 = *bsrc(t + 1, i1); }

    const int r = p / 3;          // lds row (dy = r-1)
    const int px = p - r * 3;     // hx shift (dx = px-1)
    const int abase = (r * 114 + px + lrow) * 40 + quad * 8;

    bf16x8 bf0 = *(const bf16x8*)&Blds[buf][(w * 32 + lrow) * 40 + quad * 8];
    bf16x8 bf1 = *(const bf16x8*)&Blds[buf][(w * 32 + 16 + lrow) * 40 + quad * 8];
#pragma unroll
    for (int mt = 0; mt < 7; ++mt) {
      bf16x8 a = *(const bf16x8*)&Alds[abase + mt * 16 * 40];
      acc[mt][0] = __builtin_amdgcn_mfma_f32_16x16x32_bf16(a, bf0, acc[mt][0], 0, 0, 0);
      acc[mt][1] = __builtin_amdgcn_mfma_f32_16x16x32_bf16(a, bf1, acc[mt][1], 0, 0, 0);
    }

    if (pre) {
      *(uint4*)&Blds[buf ^ 1][d0] = nb0;
      *(uint4*)&Blds[buf ^ 1][d1] = nb1;
    }
    __syncthreads();
    if (p == 8 && cc < 3) { stageA(cc + 1); __syncthreads(); }
  }

  // epilogue: C/D layout col = lane&15 (N), row = quad*4 + reg (M)
  const int k0 = w * 32 + lrow;
  const int k1 = k0 + 16;
  const float bv0 = bias[k0 < 126 ? k0 : 125];
  const float bv1 = bias[k1 < 126 ? k1 : 125];
  float* outrow = out + ((size_t)(nimg * 112 + y)) * 112 * 126;
#pragma unroll
  for (int mt = 0; mt < 7; ++mt) {
#pragma unroll
    for (int rg = 0; rg < 4; ++rg) {
      int x = mt * 16 + quad * 4 + rg;
      float* o = outrow + (size_t)x * 126;
      if (k0 < 126) { float v = acc[mt][0][rg] + bv0; o[k0] = v > 0.f ? v : 0.f; }
      if (k1 < 126) { float v = acc[mt][1][rg] + bv1; o[k1] = v > 0.f ? v : 0.f; }
    }
  }
}

extern "C" void kernel_launch(void* const* d_in, const int* in_sizes, int n_in,
                              void* d_out, int out_size, void* d_ws, size_t ws_size,
                              hipStream_t stream) {
  const float* in = (const float*)d_in[0];        // (32,112,112,128) fp32
  const float* sk = (const float*)d_in[1];        // (5,128,126) fp32
  const float* bias = (const float*)d_in[2];      // (126,) fp32
  const int* patterns = (const int*)d_in[3];      // (126,5) int32
  float* out = (float*)d_out;                     // (32,112,112,126) fp32
  unsigned short* Bws = (unsigned short*)d_ws;    // 9*4*128*32 bf16 = 294,912 B

  build_B<<<dim3(576), dim3(256), 0, stream>>>(sk, patterns, Bws);
  conv_main<<<dim3(32 * 112), dim3(256), 0, stream>>>(in, Bws, bias, out);
}

// Round 3
// 433.969 us; speedup vs baseline: 1.2101x; 1.2101x over previous
//
#include <hip/hip_runtime.h>
#include <hip/hip_bf16.h>

// SparseConv2D: 32x112x112x128 fp32 NHWC, 3x3 SAME, 126 out ch x 5 taps.
// Implicit GEMM on bf16 MFMA, dense-9-tap. M=112 (one row), N=128, K=9*128.
// R3: software-pipelined A staging (register prefetch of next cc chunk in
// flight during compute), B fragments in registers (loaded from L2-hot Bws,
// issued before A-prefetch so B waits never drain HBM loads). 7 barriers/block.

typedef __attribute__((ext_vector_type(8))) __bf16 bf16x8;
typedef __attribute__((ext_vector_type(4))) float f32x4;

__device__ __forceinline__ unsigned short f2bf(float f) {
  unsigned int u = __builtin_bit_cast(unsigned int, f);
  u += 0x7fffu + ((u >> 16) & 1u);   // RNE (inputs are finite normals)
  return (unsigned short)(u >> 16);
}

// Bws[p][cc][n][c] bf16: dense kernel, n in [0,128) (126..127 zero), c in [0,32)
__global__ __launch_bounds__(256) void build_B(const float* __restrict__ sk,
                                               const int* __restrict__ patterns,
                                               unsigned short* __restrict__ Bws) {
  int idx = blockIdx.x * 256 + threadIdx.x;
  if (idx >= 9 * 128 * 128) return;
  int c = idx & 127;
  int n = (idx >> 7) & 127;
  int p = idx >> 14;
  float v = 0.f;
  if (n < 126) {
#pragma unroll
    for (int j = 0; j < 5; ++j)
      if (patterns[n * 5 + j] == p) v = sk[(j * 128 + c) * 126 + n];
  }
  int cc = c >> 5, cl = c & 31;
  Bws[(((p * 4 + cc) * 128) + n) * 32 + cl] = f2bf(v);
}

__global__ __launch_bounds__(256, 2) void conv_main(const float* __restrict__ in,
                                                    const unsigned short* __restrict__ Bws,
                                                    const float* __restrict__ bias,
                                                    float* __restrict__ out) {
  // single A buffer: 3 halo rows x 114 px x 32ch, ch padded 32->40 (80 B rows,
  // frag reads land 2-way max on banks which is free)
  __shared__ unsigned short Alds[3 * 114 * 40];      // 27,360 B

  const int tid = threadIdx.x;
  const int bid = blockIdx.x;
  const int nimg = bid / 112;
  const int y = bid - nimg * 112;
  const int lane = tid & 63;
  const int w = tid >> 6;           // wave id: output cols [32w, 32w+32)
  const int quad = lane >> 4;
  const int lrow = lane & 15;

  const float* inb = in + (size_t)nimg * 112 * 112 * 128;

  f32x4 acc[7][2];
#pragma unroll
  for (int mt = 0; mt < 7; ++mt) { acc[mt][0] = (f32x4)0.f; acc[mt][1] = (f32x4)0.f; }

  // A prefetch: rows y-1..y+1, hx in [0,114) (gx=hx-1), 32 ch of chunk cc.
  // 3*114*8 = 2736 float4 pieces; thread handles tid + 256*it, it in [0,11).
  float4 pf[11];
  auto loadA = [&](int cc) {
#pragma unroll
    for (int it = 0; it < 11; ++it) {
      int i = tid + it * 256;
      float4 v = make_float4(0.f, 0.f, 0.f, 0.f);
      if (i < 2736) {
        int c4 = i & 7;
        int rest = i >> 3;
        int r = rest / 114;
        int hx = rest - r * 114;
        int gy = y + r - 1;
        int gx = hx - 1;
        if ((unsigned)gy < 112u && (unsigned)gx < 112u)
          v = *(const float4*)(inb + ((size_t)gy * 112 + gx) * 128 + cc * 32 + c4 * 4);
      }
      pf[it] = v;
    }
  };
  auto writeA = [&]() {
#pragma unroll
    for (int it = 0; it < 11; ++it) {
      int i = tid + it * 256;
      if (i < 2736) {
        int c4 = i & 7;
        int rest = i >> 3;
        int r = rest / 114;
        int hx = rest - r * 114;
        ushort4 s;
        s.x = f2bf(pf[it].x); s.y = f2bf(pf[it].y);
        s.z = f2bf(pf[it].z); s.w = f2bf(pf[it].w);
        *(ushort4*)&Alds[(r * 114 + hx) * 40 + c4 * 4] = s;
      }
    }
  };

  loadA(0);
  writeA();
  __syncthreads();

#pragma unroll 1
  for (int cc = 0; cc < 4; ++cc) {
    // B frags for this chunk: 9 taps x 2 n-frags, straight from global (L2-hot).
    // Issued BEFORE the A prefetch: waiting on b[p] never drains the HBM loads.
    bf16x8 b[9][2];
#pragma unroll
    for (int p = 0; p < 9; ++p)
#pragma unroll
      for (int j = 0; j < 2; ++j)
        b[p][j] = *(const bf16x8*)(Bws +
            (((size_t)(p * 4 + cc) * 128 + w * 32 + j * 16 + lrow) * 32 + quad * 8));

    if (cc < 3) loadA(cc + 1);   // HBM loads in flight during the 126 MFMAs below

#pragma unroll
    for (int p = 0; p < 9; ++p) {
      const int r = p / 3;          // dy = r-1
      const int px = p - r * 3;     // dx = px-1
      const int abase = (r * 114 + px + lrow) * 40 + quad * 8;
#pragma unroll
      for (int mt = 0; mt < 7; ++mt) {
        bf16x8 a = *(const bf16x8*)&Alds[abase + mt * 16 * 40];
        acc[mt][0] = __builtin_amdgcn_mfma_f32_16x16x32_bf16(a, b[p][0], acc[mt][0], 0, 0, 0);
        acc[mt][1] = __builtin_amdgcn_mfma_f32_16x16x32_bf16(a, b[p][1], acc[mt][1], 0, 0, 0);
      }
    }

    if (cc < 3) {
      __syncthreads();   // everyone done reading Alds[cc]
      writeA();          // waits on prefetch (hidden by the compute above)
      __syncthreads();   // Alds[cc+1] ready
    }
  }

  // epilogue: C/D layout col = lane&15 (N), row = quad*4 + reg (M)
  const int k0 = w * 32 + lrow;
  const int k1 = k0 + 16;
  const float bv0 = bias[k0 < 126 ? k0 : 125];
  const float bv1 = bias[k1 < 126 ? k1 : 125];
  float* outrow = out + ((size_t)(nimg * 112 + y)) * 112 * 126;
#pragma unroll
  for (int mt = 0; mt < 7; ++mt) {
#pragma unroll
    for (int rg = 0; rg < 4; ++rg) {
      int x = mt * 16 + quad * 4 + rg;
      float* o = outrow + (size_t)x * 126;
      if (k0 < 126) { float v = acc[mt][0][rg] + bv0; o[k0] = v > 0.f ? v : 0.f; }
      if (k1 < 126) { float v = acc[mt][1][rg] + bv1; o[k1] = v > 0.f ? v : 0.f; }
    }
  }
}

extern "C" void kernel_launch(void* const* d_in, const int* in_sizes, int n_in,
                              void* d_out, int out_size, void* d_ws, size_t ws_size,
                              hipStream_t stream) {
  const float* in = (const float*)d_in[0];        // (32,112,112,128) fp32
  const float* sk = (const float*)d_in[1];        // (5,128,126) fp32
  const float* bias = (const float*)d_in[2];      // (126,) fp32
  const int* patterns = (const int*)d_in[3];      // (126,5) int32
  float* out = (float*)d_out;                     // (32,112,112,126) fp32
  unsigned short* Bws = (unsigned short*)d_ws;    // 9*4*128*32 bf16 = 294,912 B

  build_B<<<dim3(576), dim3(256), 0, stream>>>(sk, patterns, Bws);
  conv_main<<<dim3(32 * 112), dim3(256), 0, stream>>>(in, Bws, bias, out);
}